// Round 1
// baseline (501.180 us; speedup 1.0000x reference)
//
#include <hip/hip_runtime.h>
#include <math.h>

#define FLn 96
#define SEG 288      // 3*FL
#define EPRE_DIM 192 // 2*FL
#define EPS_BN 1e-5f

__device__ __forceinline__ float lrelu(float v) { return v >= 0.f ? v : 0.1f * v; }

// ---------------- K0: transpose GEMM weights for coalesced k-major reads ----
__global__ __launch_bounds__(256) void k0_transpose(
    const float* __restrict__ rsW, const float* __restrict__ clW1,
    float* __restrict__ wT2, float* __restrict__ wT3) {
  int idx = blockIdx.x * 256 + threadIdx.x;
  int stride = gridDim.x * 256;
  for (int i = idx; i < 288 * 192; i += stride) {
    int o = i / 192, k = i - o * 192;
    wT2[k * 288 + o] = rsW[i];
  }
  for (int i = idx; i < 288 * 576; i += stride) {
    int o = i / 576, k = i - o * 576;
    wT3[k * 288 + o] = clW1[i];
  }
}

// ---------------- K1: per-(sample,half) fusion front-end -> e_pre(192) ------
__global__ __launch_bounds__(256) void k1_persample(
    const float* __restrict__ x,
    const float* __restrict__ cw1, const float* __restrict__ cb1,
    const float* __restrict__ cw2, const float* __restrict__ cb2,
    const float* __restrict__ cw3, const float* __restrict__ cb3,
    const float* __restrict__ cw4, const float* __restrict__ cb4,
    const float* __restrict__ cw5, const float* __restrict__ cb5,
    const float* __restrict__ cw6, const float* __restrict__ cb6,
    const float* __restrict__ deW, const float* __restrict__ deb,
    float* __restrict__ epre) {
  __shared__ float c_in[SEG];
  __shared__ float st1[SEG];
  __shared__ float armx[SEG];   // arm | x86 | bert
  __shared__ float aP[FLn], aN[FLn];
  __shared__ float wker[9];
  __shared__ float colpart[8 * FLn];
  __shared__ float ep[EPRE_DIM];

  const int tid = threadIdx.x;
  const int bid = blockIdx.x;          // m = samp*2 + half
  const int samp = bid >> 1;
  const int half = bid & 1;
  const float* xrow = x + samp * 576 + half * 288;

  for (int t = tid; t < SEG; t += 256) c_in[t] = xrow[t];
  __syncthreads();

  // stage-1 convs (per 96-segment, zero-padded)
  for (int t = tid; t < SEG; t += 256) {
    int seg = t / FLn, p = t - seg * FLn;
    const float* cw = seg == 0 ? cw1 : (seg == 1 ? cw2 : cw3);
    const float* cb = seg == 0 ? cb1 : (seg == 1 ? cb2 : cb3);
    float l = p > 0 ? c_in[t - 1] : 0.f;
    float m = c_in[t];
    float r = p < FLn - 1 ? c_in[t + 1] : 0.f;
    st1[t] = lrelu(cw[0] * l + cw[1] * m + cw[2] * r + cb[0]);
  }
  __syncthreads();
  // stage-2 convs
  for (int t = tid; t < SEG; t += 256) {
    int seg = t / FLn, p = t - seg * FLn;
    const float* cw = seg == 0 ? cw4 : (seg == 1 ? cw5 : cw6);
    const float* cb = seg == 0 ? cb4 : (seg == 1 ? cb5 : cb6);
    float l = p > 0 ? st1[t - 1] : 0.f;
    float m = st1[t];
    float r = p < FLn - 1 ? st1[t + 1] : 0.f;
    armx[t] = lrelu(cw[0] * l + cw[1] * m + cw[2] * r + cb[0]);
  }
  __syncthreads();
  // aP/aN: lrelu(arm_i * b) = b * (b>=0 ? aP[i] : aN[i])
  if (tid < FLn) {
    float a = armx[tid];
    float a1 = 0.1f * a;
    aP[tid] = a >= 0.f ? a : a1;
    aN[tid] = a >= 0.f ? a1 : a;
  }
  // per-sample 3x3 kernel: wker = lrelu(bert @ deW.T + deb)
  if (tid < 144) {
    int k9 = tid >> 4, l16 = tid & 15;
    float p = 0.f;
    for (int i = l16; i < FLn; i += 16) p += armx[2 * FLn + i] * deW[k9 * FLn + i];
    p += __shfl_down(p, 8, 16);
    p += __shfl_down(p, 4, 16);
    p += __shfl_down(p, 2, 16);
    p += __shfl_down(p, 1, 16);
    if (l16 == 0) wker[k9] = lrelu(p + deb[k9]);
  }
  __syncthreads();

  // fe = lrelu(conv3x3(m)), m computed on the fly with 3x5 sliding window.
  // thread tile: 12 rows (i0 = tid>>5) x 3 cols (j0 = tid&31)
  const int j0 = tid & 31;
  const int i0 = tid >> 5;
  const int jb = 3 * j0;
  const int ib = 12 * i0;
  float xx[5];
  bool sp[5];
#pragma unroll
  for (int c = 0; c < 5; ++c) {
    int jx = jb - 1 + c;
    float v = (jx >= 0 && jx < FLn) ? armx[FLn + jx] : 0.f;
    xx[c] = v;
    sp[c] = v >= 0.f;
  }
  float wk[9];
#pragma unroll
  for (int q = 0; q < 9; ++q) wk[q] = wker[q];

  float rsum[12];
  float cs0 = 0.f, cs1 = 0.f, cs2 = 0.f;
  float A[5], Bv[5], Cv[5];
  {
    int i = ib - 1;
    float ap = 0.f, an = 0.f;
    if (i >= 0) { ap = aP[i]; an = aN[i]; }
#pragma unroll
    for (int c = 0; c < 5; ++c) A[c] = xx[c] * (sp[c] ? ap : an);
  }
  {
    float ap = aP[ib], an = aN[ib];
#pragma unroll
    for (int c = 0; c < 5; ++c) Bv[c] = xx[c] * (sp[c] ? ap : an);
  }
#pragma unroll
  for (int r = 0; r < 12; ++r) {
    int i = ib + r + 1;
    float ap = 0.f, an = 0.f;
    if (i < FLn) { ap = aP[i]; an = aN[i]; }
#pragma unroll
    for (int c = 0; c < 5; ++c) Cv[c] = xx[c] * (sp[c] ? ap : an);
    float rs = 0.f;
#pragma unroll
    for (int c = 0; c < 3; ++c) {
      float s = wk[0] * A[c] + wk[1] * A[c + 1] + wk[2] * A[c + 2]
              + wk[3] * Bv[c] + wk[4] * Bv[c + 1] + wk[5] * Bv[c + 2]
              + wk[6] * Cv[c] + wk[7] * Cv[c + 1] + wk[8] * Cv[c + 2];
      float f = lrelu(s);
      rs += f;
      if (c == 0) cs0 += f;
      else if (c == 1) cs1 += f;
      else cs2 += f;
    }
    rsum[r] = rs;
#pragma unroll
    for (int c = 0; c < 5; ++c) { A[c] = Bv[c]; Bv[c] = Cv[c]; }
  }
  // row means: reduce across the 32 j0-lanes
#pragma unroll
  for (int r = 0; r < 12; ++r) {
    float v = rsum[r];
    v += __shfl_xor(v, 16, 32);
    v += __shfl_xor(v, 8, 32);
    v += __shfl_xor(v, 4, 32);
    v += __shfl_xor(v, 2, 32);
    v += __shfl_xor(v, 1, 32);
    if (j0 == 0) ep[ib + r] = v * (1.f / FLn);
  }
  colpart[i0 * FLn + jb + 0] = cs0;
  colpart[i0 * FLn + jb + 1] = cs1;
  colpart[i0 * FLn + jb + 2] = cs2;
  __syncthreads();
  if (tid < FLn) {
    float s = 0.f;
#pragma unroll
    for (int g = 0; g < 8; ++g) s += colpart[g * FLn + tid];
    ep[FLn + tid] = s * (1.f / FLn);
  }
  __syncthreads();
  float* orow = epre + bid * EPRE_DIM;
  if (tid < EPRE_DIM) orow[tid] = ep[tid];
}

// ---------------- K2: resh GEMM (16384x192x288) + BN + lrelu + residual ----
__global__ __launch_bounds__(256) void k2_resh(
    const float* __restrict__ epre, const float* __restrict__ wT2,
    const float* __restrict__ rs_b, const float* __restrict__ rs_g,
    const float* __restrict__ rs_be, const float* __restrict__ rs_m,
    const float* __restrict__ rs_v,
    const float* __restrict__ x, float* __restrict__ ce) {
  __shared__ float aT[64 * EPRE_DIM]; // 49 KB
  const int tid = threadIdx.x;
  const int row0 = blockIdx.x * 64;
  for (int idx = tid; idx < 64 * EPRE_DIM; idx += 256)
    aT[idx] = epre[row0 * EPRE_DIM + idx];
  __syncthreads();
  const int ogrp = tid & 31;
  const int rgrp = tid >> 5; // 0..7, 8 rows each
  float acc[8][9];
#pragma unroll
  for (int v = 0; v < 8; ++v)
#pragma unroll
    for (int u = 0; u < 9; ++u) acc[v][u] = 0.f;
#pragma unroll 4
  for (int k = 0; k < EPRE_DIM; ++k) {
    float wv[9];
#pragma unroll
    for (int u = 0; u < 9; ++u) wv[u] = wT2[k * 288 + ogrp + 32 * u];
#pragma unroll
    for (int v = 0; v < 8; ++v) {
      float av = aT[(rgrp + 8 * v) * EPRE_DIM + k];
#pragma unroll
      for (int u = 0; u < 9; ++u) acc[v][u] += av * wv[u];
    }
  }
#pragma unroll
  for (int u = 0; u < 9; ++u) {
    int o = ogrp + 32 * u;
    float bias = rs_b[o];
    float sc = rs_g[o] * rsqrtf(rs_v[o] + EPS_BN);
    float mu = rs_m[o], be = rs_be[o];
#pragma unroll
    for (int v = 0; v < 8; ++v) {
      int rowm = row0 + rgrp + 8 * v;
      float y = acc[v][u] + bias;
      float e = lrelu((y - mu) * sc + be);
      ce[rowm * 288 + o] = e + x[rowm * 288 + o];
    }
  }
}

// ---------------- K3: cl1 GEMM (8192x576x288) + BN + relu -> h --------------
__global__ __launch_bounds__(256) void k3_cl1(
    const float* __restrict__ ce, const float* __restrict__ wT3,
    const float* __restrict__ cl_b1, const float* __restrict__ cl_g,
    const float* __restrict__ cl_be, const float* __restrict__ cl_m,
    const float* __restrict__ cl_v, float* __restrict__ h) {
  __shared__ float aT[64 * 96]; // 24.6 KB, k-chunked
  const int tid = threadIdx.x;
  const int row0 = (blockIdx.x >> 1) * 64;
  const int out0 = (blockIdx.x & 1) * 144;
  const int ogrp = tid & 15;  // 16 out-groups: o = out0 + ogrp + 16u, u<9
  const int rgrp = tid >> 4;  // 0..15, rows r = rgrp + 16v, v<4
  float acc[4][9];
#pragma unroll
  for (int v = 0; v < 4; ++v)
#pragma unroll
    for (int u = 0; u < 9; ++u) acc[v][u] = 0.f;
  for (int kc = 0; kc < 576; kc += 96) {
    __syncthreads();
    for (int idx = tid; idx < 64 * 96; idx += 256) {
      int r = idx / 96, kk = idx - r * 96;
      aT[idx] = ce[(row0 + r) * 576 + kc + kk];
    }
    __syncthreads();
#pragma unroll 4
    for (int k = 0; k < 96; ++k) {
      float wv[9];
#pragma unroll
      for (int u = 0; u < 9; ++u)
        wv[u] = wT3[(kc + k) * 288 + out0 + ogrp + 16 * u];
#pragma unroll
      for (int v = 0; v < 4; ++v) {
        float av = aT[(rgrp + 16 * v) * 96 + k];
#pragma unroll
        for (int u = 0; u < 9; ++u) acc[v][u] += av * wv[u];
      }
    }
  }
#pragma unroll
  for (int u = 0; u < 9; ++u) {
    int o = out0 + ogrp + 16 * u;
    float bias = cl_b1[o];
    float sc = cl_g[o] * rsqrtf(cl_v[o] + EPS_BN);
    float mu = cl_m[o], be = cl_be[o];
#pragma unroll
    for (int v = 0; v < 4; ++v) {
      int rowm = row0 + rgrp + 16 * v;
      float y = acc[v][u] + bias;
      h[rowm * 288 + o] = fmaxf((y - mu) * sc + be, 0.f);
    }
  }
}

// ---------------- K4: out = h @ cl_W2.T + cl_b2 (8192x288x2) ----------------
__global__ __launch_bounds__(256) void k4_out(
    const float* __restrict__ h, const float* __restrict__ w2,
    const float* __restrict__ b2, float* __restrict__ out) {
  const int tid = threadIdx.x;
  const int row = blockIdx.x * 32 + (tid >> 3);
  const int l8 = tid & 7;
  float a0 = 0.f, a1 = 0.f;
  for (int k = l8; k < 288; k += 8) {
    float hv = h[row * 288 + k];
    a0 += hv * w2[k];
    a1 += hv * w2[288 + k];
  }
  a0 += __shfl_down(a0, 4, 8); a1 += __shfl_down(a1, 4, 8);
  a0 += __shfl_down(a0, 2, 8); a1 += __shfl_down(a1, 2, 8);
  a0 += __shfl_down(a0, 1, 8); a1 += __shfl_down(a1, 1, 8);
  if (l8 == 0) {
    out[row * 2 + 0] = a0 + b2[0];
    out[row * 2 + 1] = a1 + b2[1];
  }
}

extern "C" void kernel_launch(void* const* d_in, const int* in_sizes, int n_in,
                              void* d_out, int out_size, void* d_ws, size_t ws_size,
                              hipStream_t stream) {
  const float* x   = (const float*)d_in[0];
  const float* cw1 = (const float*)d_in[1];  const float* cb1 = (const float*)d_in[2];
  const float* cw2 = (const float*)d_in[3];  const float* cb2 = (const float*)d_in[4];
  const float* cw3 = (const float*)d_in[5];  const float* cb3 = (const float*)d_in[6];
  const float* cw4 = (const float*)d_in[7];  const float* cb4 = (const float*)d_in[8];
  const float* cw5 = (const float*)d_in[9];  const float* cb5 = (const float*)d_in[10];
  const float* cw6 = (const float*)d_in[11]; const float* cb6 = (const float*)d_in[12];
  const float* deW = (const float*)d_in[13]; const float* deb = (const float*)d_in[14];
  const float* rsW = (const float*)d_in[15]; const float* rsb = (const float*)d_in[16];
  const float* rsg = (const float*)d_in[17]; const float* rsbe = (const float*)d_in[18];
  const float* rsm = (const float*)d_in[19]; const float* rsv = (const float*)d_in[20];
  const float* clW1 = (const float*)d_in[21]; const float* clb1 = (const float*)d_in[22];
  const float* clg = (const float*)d_in[23]; const float* clbe = (const float*)d_in[24];
  const float* clm = (const float*)d_in[25]; const float* clv = (const float*)d_in[26];
  const float* clW2 = (const float*)d_in[27]; const float* clb2 = (const float*)d_in[28];

  float* ws   = (float*)d_ws;
  float* epre = ws;                      // 16384*192 floats (12.6 MB)
  float* h    = ws;                      // reuse after K2 consumed epre (9.4 MB)
  float* ce   = ws + 16384 * 192;        // 16384*288 floats (18.9 MB)
  float* wT2  = ce + 16384 * 288;        // 192*288
  float* wT3  = wT2 + 192 * 288;         // 576*288

  hipLaunchKernelGGL(k0_transpose, dim3(128), dim3(256), 0, stream, rsW, clW1, wT2, wT3);
  hipLaunchKernelGGL(k1_persample, dim3(16384), dim3(256), 0, stream, x,
                     cw1, cb1, cw2, cb2, cw3, cb3, cw4, cb4, cw5, cb5, cw6, cb6,
                     deW, deb, epre);
  hipLaunchKernelGGL(k2_resh, dim3(256), dim3(256), 0, stream,
                     epre, wT2, rsb, rsg, rsbe, rsm, rsv, x, ce);
  hipLaunchKernelGGL(k3_cl1, dim3(256), dim3(256), 0, stream,
                     ce, wT3, clb1, clg, clbe, clm, clv, h);
  hipLaunchKernelGGL(k4_out, dim3(256), dim3(256), 0, stream,
                     h, clW2, clb2, (float*)d_out);
}

// Round 2
// 382.165 us; speedup vs baseline: 1.3114x; 1.3114x over previous
//
#include <hip/hip_runtime.h>
#include <math.h>

#define FLn 96
#define SEG 288      // 3*FL
#define EPRE_DIM 192 // 2*FL
#define EPS_BN 1e-5f

__device__ __forceinline__ float lrelu(float v) { return v >= 0.f ? v : 0.1f * v; }

// ---------------- K0: transpose GEMM weights for k-major scalar reads -------
__global__ __launch_bounds__(256) void k0_transpose(
    const float* __restrict__ rsW, const float* __restrict__ clW1,
    float* __restrict__ wT2, float* __restrict__ wT3) {
  int idx = blockIdx.x * 256 + threadIdx.x;
  int stride = gridDim.x * 256;
  for (int i = idx; i < 288 * 192; i += stride) {
    int o = i / 192, k = i - o * 192;
    wT2[k * 288 + o] = rsW[i];
  }
  for (int i = idx; i < 288 * 576; i += stride) {
    int o = i / 576, k = i - o * 576;
    wT3[k * 288 + o] = clW1[i];
  }
}

// ---------------- K1: per-(sample,half) fusion front-end -> e_pre(192) ------
__global__ __launch_bounds__(256) void k1_persample(
    const float* __restrict__ x,
    const float* __restrict__ cw1, const float* __restrict__ cb1,
    const float* __restrict__ cw2, const float* __restrict__ cb2,
    const float* __restrict__ cw3, const float* __restrict__ cb3,
    const float* __restrict__ cw4, const float* __restrict__ cb4,
    const float* __restrict__ cw5, const float* __restrict__ cb5,
    const float* __restrict__ cw6, const float* __restrict__ cb6,
    const float* __restrict__ deW, const float* __restrict__ deb,
    float* __restrict__ epre) {
  __shared__ float c_in[SEG];
  __shared__ float st1[SEG];
  __shared__ float armx[SEG];   // arm | x86 | bert
  __shared__ float aP[FLn], aN[FLn];
  __shared__ float wker[9];
  __shared__ float colpart[8 * FLn];
  __shared__ float ep[EPRE_DIM];

  const int tid = threadIdx.x;
  const int bid = blockIdx.x;          // m = samp*2 + half
  const int samp = bid >> 1;
  const int half = bid & 1;
  const float* xrow = x + samp * 576 + half * 288;

  for (int t = tid; t < SEG; t += 256) c_in[t] = xrow[t];
  __syncthreads();

  // stage-1 convs (per 96-segment, zero-padded)
  for (int t = tid; t < SEG; t += 256) {
    int seg = t / FLn, p = t - seg * FLn;
    const float* cw = seg == 0 ? cw1 : (seg == 1 ? cw2 : cw3);
    const float* cb = seg == 0 ? cb1 : (seg == 1 ? cb2 : cb3);
    float l = p > 0 ? c_in[t - 1] : 0.f;
    float m = c_in[t];
    float r = p < FLn - 1 ? c_in[t + 1] : 0.f;
    st1[t] = lrelu(cw[0] * l + cw[1] * m + cw[2] * r + cb[0]);
  }
  __syncthreads();
  // stage-2 convs
  for (int t = tid; t < SEG; t += 256) {
    int seg = t / FLn, p = t - seg * FLn;
    const float* cw = seg == 0 ? cw4 : (seg == 1 ? cw5 : cw6);
    const float* cb = seg == 0 ? cb4 : (seg == 1 ? cb5 : cb6);
    float l = p > 0 ? st1[t - 1] : 0.f;
    float m = st1[t];
    float r = p < FLn - 1 ? st1[t + 1] : 0.f;
    armx[t] = lrelu(cw[0] * l + cw[1] * m + cw[2] * r + cb[0]);
  }
  __syncthreads();
  // aP/aN: lrelu(arm_i * b) = b * (b>=0 ? aP[i] : aN[i])
  if (tid < FLn) {
    float a = armx[tid];
    float a1 = 0.1f * a;
    aP[tid] = a >= 0.f ? a : a1;
    aN[tid] = a >= 0.f ? a1 : a;
  }
  // per-sample 3x3 kernel: wker = lrelu(bert @ deW.T + deb)
  if (tid < 144) {
    int k9 = tid >> 4, l16 = tid & 15;
    float p = 0.f;
    for (int i = l16; i < FLn; i += 16) p += armx[2 * FLn + i] * deW[k9 * FLn + i];
    p += __shfl_down(p, 8, 16);
    p += __shfl_down(p, 4, 16);
    p += __shfl_down(p, 2, 16);
    p += __shfl_down(p, 1, 16);
    if (l16 == 0) wker[k9] = lrelu(p + deb[k9]);
  }
  __syncthreads();

  // fe = lrelu(conv3x3(m)), m computed on the fly with 3x5 sliding window.
  // thread tile: 12 rows (i0 = tid>>5) x 3 cols (j0 = tid&31)
  const int j0 = tid & 31;
  const int i0 = tid >> 5;
  const int jb = 3 * j0;
  const int ib = 12 * i0;
  float xx[5];
  bool sp[5];
#pragma unroll
  for (int c = 0; c < 5; ++c) {
    int jx = jb - 1 + c;
    float v = (jx >= 0 && jx < FLn) ? armx[FLn + jx] : 0.f;
    xx[c] = v;
    sp[c] = v >= 0.f;
  }
  float wk[9];
#pragma unroll
  for (int q = 0; q < 9; ++q) wk[q] = wker[q];

  float rsum[12];
  float cs0 = 0.f, cs1 = 0.f, cs2 = 0.f;
  float A[5], Bv[5], Cv[5];
  {
    int i = ib - 1;
    float ap = 0.f, an = 0.f;
    if (i >= 0) { ap = aP[i]; an = aN[i]; }
#pragma unroll
    for (int c = 0; c < 5; ++c) A[c] = xx[c] * (sp[c] ? ap : an);
  }
  {
    float ap = aP[ib], an = aN[ib];
#pragma unroll
    for (int c = 0; c < 5; ++c) Bv[c] = xx[c] * (sp[c] ? ap : an);
  }
#pragma unroll
  for (int r = 0; r < 12; ++r) {
    int i = ib + r + 1;
    float ap = 0.f, an = 0.f;
    if (i < FLn) { ap = aP[i]; an = aN[i]; }
#pragma unroll
    for (int c = 0; c < 5; ++c) Cv[c] = xx[c] * (sp[c] ? ap : an);
    float rs = 0.f;
#pragma unroll
    for (int c = 0; c < 3; ++c) {
      float s = wk[0] * A[c] + wk[1] * A[c + 1] + wk[2] * A[c + 2]
              + wk[3] * Bv[c] + wk[4] * Bv[c + 1] + wk[5] * Bv[c + 2]
              + wk[6] * Cv[c] + wk[7] * Cv[c + 1] + wk[8] * Cv[c + 2];
      float f = lrelu(s);
      rs += f;
      if (c == 0) cs0 += f;
      else if (c == 1) cs1 += f;
      else cs2 += f;
    }
    rsum[r] = rs;
#pragma unroll
    for (int c = 0; c < 5; ++c) { A[c] = Bv[c]; Bv[c] = Cv[c]; }
  }
  // row means: reduce across the 32 j0-lanes
#pragma unroll
  for (int r = 0; r < 12; ++r) {
    float v = rsum[r];
    v += __shfl_xor(v, 16, 32);
    v += __shfl_xor(v, 8, 32);
    v += __shfl_xor(v, 4, 32);
    v += __shfl_xor(v, 2, 32);
    v += __shfl_xor(v, 1, 32);
    if (j0 == 0) ep[ib + r] = v * (1.f / FLn);
  }
  colpart[i0 * FLn + jb + 0] = cs0;
  colpart[i0 * FLn + jb + 1] = cs1;
  colpart[i0 * FLn + jb + 2] = cs2;
  __syncthreads();
  if (tid < FLn) {
    float s = 0.f;
#pragma unroll
    for (int g = 0; g < 8; ++g) s += colpart[g * FLn + tid];
    ep[FLn + tid] = s * (1.f / FLn);
  }
  __syncthreads();
  float* orow = epre + bid * EPRE_DIM;
  if (tid < EPRE_DIM) orow[tid] = ep[tid];
}

// ---------------- K2: resh GEMM (16384x192x288) + BN + lrelu + residual ----
// lane = row, wave owns 12 consecutive outs (scalar weight loads).
#define K2_STRIDE 194
__global__ __launch_bounds__(256) void k2_resh(
    const float* __restrict__ epre, const float* __restrict__ wT2,
    const float* __restrict__ rs_b, const float* __restrict__ rs_g,
    const float* __restrict__ rs_be, const float* __restrict__ rs_m,
    const float* __restrict__ rs_v,
    const float* __restrict__ x, float* __restrict__ ce) {
  __shared__ float aT[64 * K2_STRIDE]; // 49.7 KB
  const int tid = threadIdx.x;
  const int lane = tid & 63;
  const int wave = tid >> 6;
  const int row0 = (blockIdx.x / 6) * 64;
  const int outT = blockIdx.x % 6;     // 6 out-tiles of 48

  for (int idx = tid; idx < 64 * EPRE_DIM; idx += 256) {
    int r = idx / EPRE_DIM, kk = idx - r * EPRE_DIM;
    aT[r * K2_STRIDE + kk] = epre[(row0 + r) * EPRE_DIM + kk];
  }
  __syncthreads();

  const int out_base = __builtin_amdgcn_readfirstlane(outT * 48 + wave * 12);
  const float* wb = wT2 + out_base;
  float acc[12];
#pragma unroll
  for (int u = 0; u < 12; ++u) acc[u] = 0.f;

  const float* arow = aT + lane * K2_STRIDE;
#pragma unroll 2
  for (int k = 0; k < EPRE_DIM; k += 2) {
    float2 a2 = *(const float2*)&arow[k];
    const float* w0 = wb + k * 288;
#pragma unroll
    for (int u = 0; u < 12; ++u) acc[u] = fmaf(a2.x, w0[u], acc[u]);
#pragma unroll
    for (int u = 0; u < 12; ++u) acc[u] = fmaf(a2.y, w0[288 + u], acc[u]);
  }

  const int rowm = row0 + lane;
#pragma unroll
  for (int u = 0; u < 12; ++u) {
    int o = out_base + u;
    float y = acc[u] + rs_b[o];
    float sc = rs_g[o] * rsqrtf(rs_v[o] + EPS_BN);
    float e = lrelu((y - rs_m[o]) * sc + rs_be[o]);
    ce[rowm * 288 + o] = e + x[rowm * 288 + o];
  }
}

// ---------------- K3: cl1 GEMM (8192x576x288) + BN + relu -> h --------------
#define K3_STRIDE 98
__global__ __launch_bounds__(256) void k3_cl1(
    const float* __restrict__ ce, const float* __restrict__ wT3,
    const float* __restrict__ cl_b1, const float* __restrict__ cl_g,
    const float* __restrict__ cl_be, const float* __restrict__ cl_m,
    const float* __restrict__ cl_v, float* __restrict__ h) {
  __shared__ float aT[64 * K3_STRIDE]; // 25.1 KB
  const int tid = threadIdx.x;
  const int lane = tid & 63;
  const int wave = tid >> 6;
  const int row0 = (blockIdx.x / 6) * 64;
  const int outT = blockIdx.x % 6;

  const int out_base = __builtin_amdgcn_readfirstlane(outT * 48 + wave * 12);
  float acc[12];
#pragma unroll
  for (int u = 0; u < 12; ++u) acc[u] = 0.f;

  for (int kc = 0; kc < 576; kc += 96) {
    __syncthreads();
    for (int idx = tid; idx < 64 * 96; idx += 256) {
      int r = idx / 96, kk = idx - r * 96;
      aT[r * K3_STRIDE + kk] = ce[(row0 + r) * 576 + kc + kk];
    }
    __syncthreads();
    const float* wb = wT3 + kc * 288 + out_base;
    const float* arow = aT + lane * K3_STRIDE;
#pragma unroll 2
    for (int k = 0; k < 96; k += 2) {
      float2 a2 = *(const float2*)&arow[k];
      const float* w0 = wb + k * 288;
#pragma unroll
      for (int u = 0; u < 12; ++u) acc[u] = fmaf(a2.x, w0[u], acc[u]);
#pragma unroll
      for (int u = 0; u < 12; ++u) acc[u] = fmaf(a2.y, w0[288 + u], acc[u]);
    }
  }

  const int rowm = row0 + lane;
#pragma unroll
  for (int u = 0; u < 12; ++u) {
    int o = out_base + u;
    float y = acc[u] + cl_b1[o];
    float sc = cl_g[o] * rsqrtf(cl_v[o] + EPS_BN);
    h[rowm * 288 + o] = fmaxf((y - cl_m[o]) * sc + cl_be[o], 0.f);
  }
}

// ---------------- K4: out = h @ cl_W2.T + cl_b2 (8192x288x2) ----------------
// one wave per row, coalesced loads
__global__ __launch_bounds__(256) void k4_out(
    const float* __restrict__ h, const float* __restrict__ w2,
    const float* __restrict__ b2, float* __restrict__ out) {
  const int wave = threadIdx.x >> 6;
  const int lane = threadIdx.x & 63;
  const int row = blockIdx.x * 4 + wave;
  const float* hr = h + row * 288;
  float a0 = 0.f, a1 = 0.f;
#pragma unroll
  for (int i = 0; i < 5; ++i) {
    int k = lane + 64 * i;
    if (k < 288) {
      float hv = hr[k];
      a0 = fmaf(hv, w2[k], a0);
      a1 = fmaf(hv, w2[288 + k], a1);
    }
  }
#pragma unroll
  for (int off = 32; off; off >>= 1) {
    a0 += __shfl_xor(a0, off, 64);
    a1 += __shfl_xor(a1, off, 64);
  }
  if (lane == 0) {
    out[row * 2 + 0] = a0 + b2[0];
    out[row * 2 + 1] = a1 + b2[1];
  }
}

extern "C" void kernel_launch(void* const* d_in, const int* in_sizes, int n_in,
                              void* d_out, int out_size, void* d_ws, size_t ws_size,
                              hipStream_t stream) {
  const float* x   = (const float*)d_in[0];
  const float* cw1 = (const float*)d_in[1];  const float* cb1 = (const float*)d_in[2];
  const float* cw2 = (const float*)d_in[3];  const float* cb2 = (const float*)d_in[4];
  const float* cw3 = (const float*)d_in[5];  const float* cb3 = (const float*)d_in[6];
  const float* cw4 = (const float*)d_in[7];  const float* cb4 = (const float*)d_in[8];
  const float* cw5 = (const float*)d_in[9];  const float* cb5 = (const float*)d_in[10];
  const float* cw6 = (const float*)d_in[11]; const float* cb6 = (const float*)d_in[12];
  const float* deW = (const float*)d_in[13]; const float* deb = (const float*)d_in[14];
  const float* rsW = (const float*)d_in[15]; const float* rsb = (const float*)d_in[16];
  const float* rsg = (const float*)d_in[17]; const float* rsbe = (const float*)d_in[18];
  const float* rsm = (const float*)d_in[19]; const float* rsv = (const float*)d_in[20];
  const float* clW1 = (const float*)d_in[21]; const float* clb1 = (const float*)d_in[22];
  const float* clg = (const float*)d_in[23]; const float* clbe = (const float*)d_in[24];
  const float* clm = (const float*)d_in[25]; const float* clv = (const float*)d_in[26];
  const float* clW2 = (const float*)d_in[27]; const float* clb2 = (const float*)d_in[28];

  float* ws   = (float*)d_ws;
  float* epre = ws;                      // 16384*192 floats (12.6 MB)
  float* h    = ws;                      // reuse after K2 consumed epre (9.4 MB)
  float* ce   = ws + 16384 * 192;        // 16384*288 floats (18.9 MB)
  float* wT2  = ce + 16384 * 288;        // 192*288
  float* wT3  = wT2 + 192 * 288;         // 576*288

  hipLaunchKernelGGL(k0_transpose, dim3(128), dim3(256), 0, stream, rsW, clW1, wT2, wT3);
  hipLaunchKernelGGL(k1_persample, dim3(16384), dim3(256), 0, stream, x,
                     cw1, cb1, cw2, cb2, cw3, cb3, cw4, cb4, cw5, cb5, cw6, cb6,
                     deW, deb, epre);
  hipLaunchKernelGGL(k2_resh, dim3(256 * 6), dim3(256), 0, stream,
                     epre, wT2, rsb, rsg, rsbe, rsm, rsv, x, ce);
  hipLaunchKernelGGL(k3_cl1, dim3(128 * 6), dim3(256), 0, stream,
                     ce, wT3, clb1, clg, clbe, clm, clv, h);
  hipLaunchKernelGGL(k4_out, dim3(2048), dim3(256), 0, stream,
                     h, clW2, clb2, (float*)d_out);
}

// Round 3
// 335.412 us; speedup vs baseline: 1.4942x; 1.1394x over previous
//
#include <hip/hip_runtime.h>
#include <math.h>

#define FLn 96
#define SEG 288      // 3*FL
#define EPRE_DIM 192 // 2*FL
#define EPS_BN 1e-5f

__device__ __forceinline__ float lrelu(float v) { return fmaxf(v, 0.1f * v); }

// ---------------- K0: transpose GEMM weights for k-major reads --------------
__global__ __launch_bounds__(256) void k0_transpose(
    const float* __restrict__ rsW, const float* __restrict__ clW1,
    float* __restrict__ wT2, float* __restrict__ wT3) {
  int idx = blockIdx.x * 256 + threadIdx.x;
  int stride = gridDim.x * 256;
  for (int i = idx; i < 288 * 192; i += stride) {
    int o = i / 192, k = i - o * 192;
    wT2[k * 288 + o] = rsW[i];
  }
  for (int i = idx; i < 288 * 576; i += stride) {
    int o = i / 576, k = i - o * 576;
    wT3[k * 288 + o] = clW1[i];
  }
}

// ---------------- K1: per-(sample,half) fusion front-end -> e_pre(192) ------
// lrelu = max(p, 0.1p): no masks/bools. Padded LDS arrays: no boundary branches.
// Thread tile: 3 rows x 12 cols of fe. 9 shuffles total for row means.
__global__ __launch_bounds__(256) void k1_persample(
    const float* __restrict__ x,
    const float* __restrict__ cw1, const float* __restrict__ cb1,
    const float* __restrict__ cw2, const float* __restrict__ cb2,
    const float* __restrict__ cw3, const float* __restrict__ cb3,
    const float* __restrict__ cw4, const float* __restrict__ cb4,
    const float* __restrict__ cw5, const float* __restrict__ cb5,
    const float* __restrict__ cw6, const float* __restrict__ cb6,
    const float* __restrict__ deW, const float* __restrict__ deb,
    float* __restrict__ epre) {
  __shared__ float c_in[SEG];
  __shared__ float st1[SEG];
  // pk layout: armP = pk[0..97] (pad at 0,97), x86P = pk[100..197] (pad 100,197),
  // bert = pk[200..295]. 16B-aligned sub-bases (0, 100*4=400%16==0, 200*4 %16==0).
  __shared__ float pk[296];
  __shared__ float wker[9];
  __shared__ float colpart[32 * FLn]; // 12 KB
  __shared__ float ep[EPRE_DIM];

  const int tid = threadIdx.x;
  const int bid = blockIdx.x;          // m = samp*2 + half
  const float* xrow = x + (bid >> 1) * 576 + (bid & 1) * 288;

  // uniform scalar weight loads (s_load)
  const float a0w0 = cw1[0], a0w1 = cw1[1], a0w2 = cw1[2], a0b = cb1[0];
  const float a1w0 = cw2[0], a1w1 = cw2[1], a1w2 = cw2[2], a1b = cb2[0];
  const float a2w0 = cw3[0], a2w1 = cw3[1], a2w2 = cw3[2], a2b = cb3[0];
  const float b0w0 = cw4[0], b0w1 = cw4[1], b0w2 = cw4[2], b0b = cb4[0];
  const float b1w0 = cw5[0], b1w1 = cw5[1], b1w2 = cw5[2], b1b = cb5[0];
  const float b2w0 = cw6[0], b2w1 = cw6[1], b2w2 = cw6[2], b2b = cb6[0];

  if (tid < 72) ((float4*)c_in)[tid] = ((const float4*)xrow)[tid];
  __syncthreads();

  // stage-1 convs
  for (int t = tid; t < SEG; t += 256) {
    bool g1 = t >= 96, g2 = t >= 192;
    float wa = g2 ? a2w0 : (g1 ? a1w0 : a0w0);
    float wb = g2 ? a2w1 : (g1 ? a1w1 : a0w1);
    float wc = g2 ? a2w2 : (g1 ? a1w2 : a0w2);
    float bb = g2 ? a2b  : (g1 ? a1b  : a0b);
    int p = t - (g2 ? 192 : (g1 ? 96 : 0));
    float l = p > 0 ? c_in[t - 1] : 0.f;
    float m = c_in[t];
    float r = p < FLn - 1 ? c_in[t + 1] : 0.f;
    st1[t] = lrelu(fmaf(wa, l, fmaf(wb, m, fmaf(wc, r, bb))));
  }
  __syncthreads();
  // stage-2 convs -> pk (padded layout)
  for (int t = tid; t < SEG; t += 256) {
    bool g1 = t >= 96, g2 = t >= 192;
    float wa = g2 ? b2w0 : (g1 ? b1w0 : b0w0);
    float wb = g2 ? b2w1 : (g1 ? b1w1 : b0w1);
    float wc = g2 ? b2w2 : (g1 ? b1w2 : b0w2);
    float bb = g2 ? b2b  : (g1 ? b1b  : b0b);
    int p = t - (g2 ? 192 : (g1 ? 96 : 0));
    float l = p > 0 ? st1[t - 1] : 0.f;
    float m = st1[t];
    float r = p < FLn - 1 ? st1[t + 1] : 0.f;
    int dst = t + (g2 ? 8 : (g1 ? 5 : 1)); // armP[1+p] / x86P[1+p] / bert[p]
    pk[dst] = lrelu(fmaf(wa, l, fmaf(wb, m, fmaf(wc, r, bb))));
  }
  __syncthreads();
  // per-sample 3x3 kernel: wker = lrelu(bert @ deW.T + deb)
  if (tid < 144) {
    int k9 = tid >> 4, l16 = tid & 15;
    float p = 0.f;
    for (int i = l16; i < FLn; i += 16) p = fmaf(pk[200 + i], deW[k9 * FLn + i], p);
    p += __shfl_down(p, 8, 16);
    p += __shfl_down(p, 4, 16);
    p += __shfl_down(p, 2, 16);
    p += __shfl_down(p, 1, 16);
    if (l16 == 0) wker[k9] = lrelu(p + deb[k9]);
  } else if (tid >= 252) {
    int z = tid - 252;
    if (z == 0) pk[0] = 0.f;
    else if (z == 1) pk[97] = 0.f;
    else if (z == 2) pk[100] = 0.f;
    else pk[197] = 0.f;
  }
  __syncthreads();

  // main conv: thread tile 3 rows (trr = tid>>3) x 12 cols (tc = tid&7)
  const int tc = tid & 7;
  const int trr = tid >> 3;
  const int jb = tc * 12;
  const int ib = trr * 3;

  float xx[14];
  {
    float4 v0 = *(const float4*)&pk[100 + jb];
    float4 v1 = *(const float4*)&pk[100 + jb + 4];
    float4 v2 = *(const float4*)&pk[100 + jb + 8];
    float2 v3 = *(const float2*)&pk[100 + jb + 12];
    xx[0]=v0.x; xx[1]=v0.y; xx[2]=v0.z; xx[3]=v0.w;
    xx[4]=v1.x; xx[5]=v1.y; xx[6]=v1.z; xx[7]=v1.w;
    xx[8]=v2.x; xx[9]=v2.y; xx[10]=v2.z; xx[11]=v2.w;
    xx[12]=v3.x; xx[13]=v3.y;
  }
  float wk[9];
#pragma unroll
  for (int q = 0; q < 9; ++q) wk[q] = wker[q];

  float acc[3][12];
#pragma unroll
  for (int r = 0; r < 3; ++r)
#pragma unroll
    for (int j = 0; j < 12; ++j) acc[r][j] = 0.f;

#pragma unroll
  for (int wr = 0; wr < 5; ++wr) {
    float a = pk[ib + wr];   // armP, zero-padded
    float mrow[14];
#pragma unroll
    for (int c = 0; c < 14; ++c) {
      float p = a * xx[c];
      mrow[c] = fmaxf(p, 0.1f * p);
    }
    const int rlo = wr - 2 > 0 ? wr - 2 : 0;
    const int rhi = wr < 2 ? wr : 2;
#pragma unroll
    for (int r = 0; r < 3; ++r) {
      if (r >= rlo && r <= rhi) {
        const int ki = wr - r;
#pragma unroll
        for (int j = 0; j < 12; ++j) {
          acc[r][j] = fmaf(wk[ki * 3 + 0], mrow[j], acc[r][j]);
          acc[r][j] = fmaf(wk[ki * 3 + 1], mrow[j + 1], acc[r][j]);
          acc[r][j] = fmaf(wk[ki * 3 + 2], mrow[j + 2], acc[r][j]);
        }
      }
    }
  }

  // lrelu + row/col sums
  float cp[12];
#pragma unroll
  for (int j = 0; j < 12; ++j) cp[j] = 0.f;
#pragma unroll
  for (int r = 0; r < 3; ++r) {
    float rs = 0.f;
#pragma unroll
    for (int j = 0; j < 12; ++j) {
      float s = acc[r][j];
      float f = fmaxf(s, 0.1f * s);
      rs += f;
      cp[j] += f;
    }
    rs += __shfl_xor(rs, 1, 64);
    rs += __shfl_xor(rs, 2, 64);
    rs += __shfl_xor(rs, 4, 64);
    if (tc == 0) ep[ib + r] = rs * (1.f / FLn);
  }
  {
    float* cpd = &colpart[trr * FLn + jb];
    ((float4*)cpd)[0] = make_float4(cp[0], cp[1], cp[2], cp[3]);
    ((float4*)cpd)[1] = make_float4(cp[4], cp[5], cp[6], cp[7]);
    ((float4*)cpd)[2] = make_float4(cp[8], cp[9], cp[10], cp[11]);
  }
  __syncthreads();
  if (tid < FLn) {
    float s = 0.f;
#pragma unroll
    for (int g = 0; g < 32; ++g) s += colpart[g * FLn + tid];
    ep[FLn + tid] = s * (1.f / FLn);
  }
  __syncthreads();
  if (tid < 48) ((float4*)(epre + bid * EPRE_DIM))[tid] = ((float4*)ep)[tid];
}

// ---------------- K2/K3: outer-product tiled fp32 GEMM ---------------------
// tile 128 rows x 48 outs, 192 threads, micro 8x4, K-chunk 48.
// act LDS layout: phys(r) = r + (r>>3)*2 (stride-10 groups -> all banks distinct)
#define GT_AP 160   // floats per k row in aT (16 groups * 10)
#define GT_CH 48

// epilogue_mode: 0 = BN+lrelu+residual(x) -> ce ; 1 = BN+relu -> h
template <int AS, int KTOT, int MODE>
__global__ __launch_bounds__(192) void gemm_tiled(
    const float* __restrict__ A, const float* __restrict__ WT,
    const float* __restrict__ bb, const float* __restrict__ gg,
    const float* __restrict__ be, const float* __restrict__ mm,
    const float* __restrict__ vv,
    const float* __restrict__ resid, float* __restrict__ out) {
  __shared__ float aT[GT_CH * GT_AP]; // 30.7 KB
  __shared__ float wL[GT_CH * 48];    // 9.2 KB
  const int tid = threadIdx.x;
  const int tc = tid % 12;
  const int tr = tid / 12;
  const int row0 = (blockIdx.x / 6) * 128;
  const int out0 = (blockIdx.x % 6) * 48;

  float acc[8][4];
#pragma unroll
  for (int q = 0; q < 8; ++q)
#pragma unroll
    for (int u = 0; u < 4; ++u) acc[q][u] = 0.f;

  for (int kc = 0; kc < KTOT; kc += GT_CH) {
    __syncthreads();
    for (int i = tid; i < 128 * 12; i += 192) {
      int r = i / 12;
      int kb = (i - r * 12) * 4;
      float4 v = *(const float4*)&A[(size_t)(row0 + r) * AS + kc + kb];
      int ph = r + ((r >> 3) << 1);
      aT[(kb + 0) * GT_AP + ph] = v.x;
      aT[(kb + 1) * GT_AP + ph] = v.y;
      aT[(kb + 2) * GT_AP + ph] = v.z;
      aT[(kb + 3) * GT_AP + ph] = v.w;
    }
    for (int i = tid; i < GT_CH * 12; i += 192) {
      int k = i / 12;
      int ob = (i - k * 12) * 4;
      *(float4*)&wL[k * 48 + ob] = *(const float4*)&WT[(size_t)(kc + k) * 288 + out0 + ob];
    }
    __syncthreads();
    const float* ap = aT + tr * 10;
    const float* wp = wL + tc * 4;
#pragma unroll 4
    for (int k = 0; k < GT_CH; ++k) {
      float2 a01 = *(const float2*)&ap[k * GT_AP];
      float2 a23 = *(const float2*)&ap[k * GT_AP + 2];
      float2 a45 = *(const float2*)&ap[k * GT_AP + 4];
      float2 a67 = *(const float2*)&ap[k * GT_AP + 6];
      float4 w = *(const float4*)&wp[k * 48];
      float av[8] = {a01.x, a01.y, a23.x, a23.y, a45.x, a45.y, a67.x, a67.y};
#pragma unroll
      for (int q = 0; q < 8; ++q) {
        acc[q][0] = fmaf(av[q], w.x, acc[q][0]);
        acc[q][1] = fmaf(av[q], w.y, acc[q][1]);
        acc[q][2] = fmaf(av[q], w.z, acc[q][2]);
        acc[q][3] = fmaf(av[q], w.w, acc[q][3]);
      }
    }
  }

  const int o0 = out0 + tc * 4;
  float4 vb = *(const float4*)&bb[o0];
  float4 vg = *(const float4*)&gg[o0];
  float4 vbe = *(const float4*)&be[o0];
  float4 vm = *(const float4*)&mm[o0];
  float4 vv4 = *(const float4*)&vv[o0];
  float4 sc;
  sc.x = vg.x * rsqrtf(vv4.x + EPS_BN);
  sc.y = vg.y * rsqrtf(vv4.y + EPS_BN);
  sc.z = vg.z * rsqrtf(vv4.z + EPS_BN);
  sc.w = vg.w * rsqrtf(vv4.w + EPS_BN);
#pragma unroll
  for (int q = 0; q < 8; ++q) {
    int rm = row0 + tr * 8 + q;
    float4 o;
    o.x = (acc[q][0] + vb.x - vm.x) * sc.x + vbe.x;
    o.y = (acc[q][1] + vb.y - vm.y) * sc.y + vbe.y;
    o.z = (acc[q][2] + vb.z - vm.z) * sc.z + vbe.z;
    o.w = (acc[q][3] + vb.w - vm.w) * sc.w + vbe.w;
    if (MODE == 0) {
      float4 rr = *(const float4*)&resid[(size_t)rm * 288 + o0];
      o.x = lrelu(o.x) + rr.x;
      o.y = lrelu(o.y) + rr.y;
      o.z = lrelu(o.z) + rr.z;
      o.w = lrelu(o.w) + rr.w;
    } else {
      o.x = fmaxf(o.x, 0.f);
      o.y = fmaxf(o.y, 0.f);
      o.z = fmaxf(o.z, 0.f);
      o.w = fmaxf(o.w, 0.f);
    }
    *(float4*)&out[(size_t)rm * 288 + o0] = o;
  }
}

// ---------------- K4: out = h @ cl_W2.T + cl_b2 (8192x288x2) ----------------
__global__ __launch_bounds__(256) void k4_out(
    const float* __restrict__ h, const float* __restrict__ w2,
    const float* __restrict__ b2, float* __restrict__ out) {
  const int wave = threadIdx.x >> 6;
  const int lane = threadIdx.x & 63;
  const int row = blockIdx.x * 4 + wave;
  const float* hr = h + (size_t)row * 288;
  float a0 = 0.f, a1 = 0.f;
#pragma unroll
  for (int i = 0; i < 5; ++i) {
    int k = lane + 64 * i;
    if (k < 288) {
      float hv = hr[k];
      a0 = fmaf(hv, w2[k], a0);
      a1 = fmaf(hv, w2[288 + k], a1);
    }
  }
#pragma unroll
  for (int off = 32; off; off >>= 1) {
    a0 += __shfl_xor(a0, off, 64);
    a1 += __shfl_xor(a1, off, 64);
  }
  if (lane == 0) {
    out[row * 2 + 0] = a0 + b2[0];
    out[row * 2 + 1] = a1 + b2[1];
  }
}

extern "C" void kernel_launch(void* const* d_in, const int* in_sizes, int n_in,
                              void* d_out, int out_size, void* d_ws, size_t ws_size,
                              hipStream_t stream) {
  const float* x   = (const float*)d_in[0];
  const float* cw1 = (const float*)d_in[1];  const float* cb1 = (const float*)d_in[2];
  const float* cw2 = (const float*)d_in[3];  const float* cb2 = (const float*)d_in[4];
  const float* cw3 = (const float*)d_in[5];  const float* cb3 = (const float*)d_in[6];
  const float* cw4 = (const float*)d_in[7];  const float* cb4 = (const float*)d_in[8];
  const float* cw5 = (const float*)d_in[9];  const float* cb5 = (const float*)d_in[10];
  const float* cw6 = (const float*)d_in[11]; const float* cb6 = (const float*)d_in[12];
  const float* deW = (const float*)d_in[13]; const float* deb = (const float*)d_in[14];
  const float* rsW = (const float*)d_in[15]; const float* rsb = (const float*)d_in[16];
  const float* rsg = (const float*)d_in[17]; const float* rsbe = (const float*)d_in[18];
  const float* rsm = (const float*)d_in[19]; const float* rsv = (const float*)d_in[20];
  const float* clW1 = (const float*)d_in[21]; const float* clb1 = (const float*)d_in[22];
  const float* clg = (const float*)d_in[23]; const float* clbe = (const float*)d_in[24];
  const float* clm = (const float*)d_in[25]; const float* clv = (const float*)d_in[26];
  const float* clW2 = (const float*)d_in[27]; const float* clb2 = (const float*)d_in[28];

  float* ws   = (float*)d_ws;
  float* epre = ws;                      // 16384*192 floats
  float* h    = ws;                      // reuse after K2 consumed epre
  float* ce   = ws + 16384 * 192;        // 16384*288 floats
  float* wT2  = ce + 16384 * 288;        // 192*288
  float* wT3  = wT2 + 192 * 288;         // 576*288

  hipLaunchKernelGGL(k0_transpose, dim3(128), dim3(256), 0, stream, rsW, clW1, wT2, wT3);
  hipLaunchKernelGGL(k1_persample, dim3(16384), dim3(256), 0, stream, x,
                     cw1, cb1, cw2, cb2, cw3, cb3, cw4, cb4, cw5, cb5, cw6, cb6,
                     deW, deb, epre);
  // K2: M=16384, K=192, A=epre, residual=x -> ce
  hipLaunchKernelGGL((gemm_tiled<192, 192, 0>), dim3(128 * 6), dim3(192), 0, stream,
                     epre, wT2, rsb, rsg, rsbe, rsm, rsv, x, ce);
  // K3: M=8192, K=576, A=ce -> h
  hipLaunchKernelGGL((gemm_tiled<576, 576, 1>), dim3(64 * 6), dim3(192), 0, stream,
                     ce, wT3, clb1, clg, clbe, clm, clv, (const float*)nullptr, h);
  hipLaunchKernelGGL(k4_out, dim3(2048), dim3(256), 0, stream,
                     h, clW2, clb2, (float*)d_out);
}

// Round 4
// 231.595 us; speedup vs baseline: 2.1640x; 1.4483x over previous
//
#include <hip/hip_runtime.h>
#include <hip/hip_bf16.h>
#include <math.h>

#define FLn 96
#define SEG 288      // 3*FL
#define EPRE_DIM 192 // 2*FL
#define EPS_BN 1e-5f

typedef __attribute__((ext_vector_type(8))) short short8;
typedef __attribute__((ext_vector_type(4))) float floatx4;

__device__ __forceinline__ float lrelu(float v) { return fmaxf(v, 0.1f * v); }

// ---------------- K0: cast GEMM weights to bf16 ([out][k] layout kept) ------
__global__ __launch_bounds__(256) void k0_cast(
    const float* __restrict__ rsW, const float* __restrict__ clW1,
    __hip_bfloat16* __restrict__ wB2, __hip_bfloat16* __restrict__ wB3) {
  int idx = blockIdx.x * 256 + threadIdx.x;
  int stride = gridDim.x * 256;
  for (int i = idx; i < 288 * 192; i += stride) wB2[i] = __float2bfloat16(rsW[i]);
  for (int i = idx; i < 288 * 576; i += stride) wB3[i] = __float2bfloat16(clW1[i]);
}

// ---------------- K1: per-(sample,half) fusion front-end -> e_pre(192) bf16 -
__global__ __launch_bounds__(256) void k1_persample(
    const float* __restrict__ x,
    const float* __restrict__ cw1, const float* __restrict__ cb1,
    const float* __restrict__ cw2, const float* __restrict__ cb2,
    const float* __restrict__ cw3, const float* __restrict__ cb3,
    const float* __restrict__ cw4, const float* __restrict__ cb4,
    const float* __restrict__ cw5, const float* __restrict__ cb5,
    const float* __restrict__ cw6, const float* __restrict__ cb6,
    const float* __restrict__ deW, const float* __restrict__ deb,
    __hip_bfloat16* __restrict__ epre) {
  __shared__ float c_in[SEG];
  __shared__ float st1[SEG];
  // pk layout: armP = pk[0..97] (pad 0,97), x86P = pk[100..197] (pad 100,197),
  // bert = pk[200..295].
  __shared__ float pk[296];
  __shared__ float wker[9];
  __shared__ float colpart[32 * FLn];
  __shared__ float ep[EPRE_DIM];

  const int tid = threadIdx.x;
  const int bid = blockIdx.x;          // m = samp*2 + half
  const float* xrow = x + (bid >> 1) * 576 + (bid & 1) * 288;

  const float a0w0 = cw1[0], a0w1 = cw1[1], a0w2 = cw1[2], a0b = cb1[0];
  const float a1w0 = cw2[0], a1w1 = cw2[1], a1w2 = cw2[2], a1b = cb2[0];
  const float a2w0 = cw3[0], a2w1 = cw3[1], a2w2 = cw3[2], a2b = cb3[0];
  const float b0w0 = cw4[0], b0w1 = cw4[1], b0w2 = cw4[2], b0b = cb4[0];
  const float b1w0 = cw5[0], b1w1 = cw5[1], b1w2 = cw5[2], b1b = cb5[0];
  const float b2w0 = cw6[0], b2w1 = cw6[1], b2w2 = cw6[2], b2b = cb6[0];

  if (tid < 72) ((float4*)c_in)[tid] = ((const float4*)xrow)[tid];
  __syncthreads();

  for (int t = tid; t < SEG; t += 256) {
    bool g1 = t >= 96, g2 = t >= 192;
    float wa = g2 ? a2w0 : (g1 ? a1w0 : a0w0);
    float wb = g2 ? a2w1 : (g1 ? a1w1 : a0w1);
    float wc = g2 ? a2w2 : (g1 ? a1w2 : a0w2);
    float bb = g2 ? a2b  : (g1 ? a1b  : a0b);
    int p = t - (g2 ? 192 : (g1 ? 96 : 0));
    float l = p > 0 ? c_in[t - 1] : 0.f;
    float m = c_in[t];
    float r = p < FLn - 1 ? c_in[t + 1] : 0.f;
    st1[t] = lrelu(fmaf(wa, l, fmaf(wb, m, fmaf(wc, r, bb))));
  }
  __syncthreads();
  for (int t = tid; t < SEG; t += 256) {
    bool g1 = t >= 96, g2 = t >= 192;
    float wa = g2 ? b2w0 : (g1 ? b1w0 : b0w0);
    float wb = g2 ? b2w1 : (g1 ? b1w1 : b0w1);
    float wc = g2 ? b2w2 : (g1 ? b1w2 : b0w2);
    float bb = g2 ? b2b  : (g1 ? b1b  : b0b);
    int p = t - (g2 ? 192 : (g1 ? 96 : 0));
    float l = p > 0 ? st1[t - 1] : 0.f;
    float m = st1[t];
    float r = p < FLn - 1 ? st1[t + 1] : 0.f;
    int dst = t + (g2 ? 8 : (g1 ? 5 : 1));
    pk[dst] = lrelu(fmaf(wa, l, fmaf(wb, m, fmaf(wc, r, bb))));
  }
  __syncthreads();
  if (tid < 144) {
    int k9 = tid >> 4, l16 = tid & 15;
    float p = 0.f;
    for (int i = l16; i < FLn; i += 16) p = fmaf(pk[200 + i], deW[k9 * FLn + i], p);
    p += __shfl_down(p, 8, 16);
    p += __shfl_down(p, 4, 16);
    p += __shfl_down(p, 2, 16);
    p += __shfl_down(p, 1, 16);
    if (l16 == 0) wker[k9] = lrelu(p + deb[k9]);
  } else if (tid >= 252) {
    int z = tid - 252;
    if (z == 0) pk[0] = 0.f;
    else if (z == 1) pk[97] = 0.f;
    else if (z == 2) pk[100] = 0.f;
    else pk[197] = 0.f;
  }
  __syncthreads();

  const int tc = tid & 7;
  const int trr = tid >> 3;
  const int jb = tc * 12;
  const int ib = trr * 3;

  float xx[14];
  {
    float4 v0 = *(const float4*)&pk[100 + jb];
    float4 v1 = *(const float4*)&pk[100 + jb + 4];
    float4 v2 = *(const float4*)&pk[100 + jb + 8];
    float2 v3 = *(const float2*)&pk[100 + jb + 12];
    xx[0]=v0.x; xx[1]=v0.y; xx[2]=v0.z; xx[3]=v0.w;
    xx[4]=v1.x; xx[5]=v1.y; xx[6]=v1.z; xx[7]=v1.w;
    xx[8]=v2.x; xx[9]=v2.y; xx[10]=v2.z; xx[11]=v2.w;
    xx[12]=v3.x; xx[13]=v3.y;
  }
  float wk[9];
#pragma unroll
  for (int q = 0; q < 9; ++q) wk[q] = wker[q];

  float acc[3][12];
#pragma unroll
  for (int r = 0; r < 3; ++r)
#pragma unroll
    for (int j = 0; j < 12; ++j) acc[r][j] = 0.f;

#pragma unroll
  for (int wr = 0; wr < 5; ++wr) {
    float a = pk[ib + wr];
    float mrow[14];
#pragma unroll
    for (int c = 0; c < 14; ++c) {
      float p = a * xx[c];
      mrow[c] = fmaxf(p, 0.1f * p);
    }
    const int rlo = wr - 2 > 0 ? wr - 2 : 0;
    const int rhi = wr < 2 ? wr : 2;
#pragma unroll
    for (int r = 0; r < 3; ++r) {
      if (r >= rlo && r <= rhi) {
        const int ki = wr - r;
#pragma unroll
        for (int j = 0; j < 12; ++j) {
          acc[r][j] = fmaf(wk[ki * 3 + 0], mrow[j], acc[r][j]);
          acc[r][j] = fmaf(wk[ki * 3 + 1], mrow[j + 1], acc[r][j]);
          acc[r][j] = fmaf(wk[ki * 3 + 2], mrow[j + 2], acc[r][j]);
        }
      }
    }
  }

  float cp[12];
#pragma unroll
  for (int j = 0; j < 12; ++j) cp[j] = 0.f;
#pragma unroll
  for (int r = 0; r < 3; ++r) {
    float rs = 0.f;
#pragma unroll
    for (int j = 0; j < 12; ++j) {
      float s = acc[r][j];
      float f = fmaxf(s, 0.1f * s);
      rs += f;
      cp[j] += f;
    }
    rs += __shfl_xor(rs, 1, 64);
    rs += __shfl_xor(rs, 2, 64);
    rs += __shfl_xor(rs, 4, 64);
    if (tc == 0) ep[ib + r] = rs * (1.f / FLn);
  }
  {
    float* cpd = &colpart[trr * FLn + jb];
    ((float4*)cpd)[0] = make_float4(cp[0], cp[1], cp[2], cp[3]);
    ((float4*)cpd)[1] = make_float4(cp[4], cp[5], cp[6], cp[7]);
    ((float4*)cpd)[2] = make_float4(cp[8], cp[9], cp[10], cp[11]);
  }
  __syncthreads();
  if (tid < FLn) {
    float s = 0.f;
#pragma unroll
    for (int g = 0; g < 32; ++g) s += colpart[g * FLn + tid];
    ep[FLn + tid] = s * (1.f / FLn);
  }
  __syncthreads();
  if (tid < EPRE_DIM) epre[bid * EPRE_DIM + tid] = __float2bfloat16(ep[tid]);
}

// ---------------- K2/K3: bf16 MFMA GEMM, BM=128 BN=32 BK=32 -----------------
// A: [M][AS] bf16 row-major. W: [288][KTOT] bf16 row-major ([out][k]).
// wave tile 32Mx32N: 2 A-frags x 2 B-frags, mfma_f32_16x16x32_bf16.
// LDS rows padded to 40 shorts (80 B) -> worst-case 2-way bank alias (free).
// MODE 0: BN+lrelu+residual(x fp32) -> out bf16. MODE 1: BN+relu -> out bf16.
template <int AS, int KTOT, int MODE>
__global__ __launch_bounds__(256) void gemm_mfma(
    const short* __restrict__ A, const short* __restrict__ W,
    const float* __restrict__ bb, const float* __restrict__ gg,
    const float* __restrict__ be, const float* __restrict__ mm,
    const float* __restrict__ vv,
    const float* __restrict__ resid, __hip_bfloat16* __restrict__ out) {
  __shared__ short sA[128 * 40]; // 10 KB
  __shared__ short sB[32 * 40];  // 2.5 KB
  const int tid = threadIdx.x;
  const int lane = tid & 63;
  const int w = tid >> 6;
  const int quad = lane >> 4;
  const int l16 = lane & 15;
  const int row0 = (blockIdx.x / 9) * 128;
  const int out0 = (blockIdx.x % 9) * 32;

  floatx4 acc[2][2];
#pragma unroll
  for (int mi = 0; mi < 2; ++mi)
#pragma unroll
    for (int ni = 0; ni < 2; ++ni) acc[mi][ni] = (floatx4){0.f, 0.f, 0.f, 0.f};

  const int ar = tid >> 1;        // staging: row for A
  const int ah = tid & 1;         // which 16-short half
  for (int kc = 0; kc < KTOT; kc += 32) {
    {
      // A tile: 128 rows x 32 shorts
      const float4* src = (const float4*)&A[(size_t)(row0 + ar) * AS + kc + ah * 16];
      float4 v0 = src[0];
      float4 v1 = src[1];
      *(float4*)&sA[ar * 40 + ah * 16] = v0;
      *(float4*)&sA[ar * 40 + ah * 16 + 8] = v1;
      // B tile: 32 n-rows x 32 shorts
      if (tid < 64) {
        const float4* bs = (const float4*)&W[(size_t)(out0 + ar) * KTOT + kc + ah * 16];
        float4 u0 = bs[0];
        float4 u1 = bs[1];
        *(float4*)&sB[ar * 40 + ah * 16] = u0;
        *(float4*)&sB[ar * 40 + ah * 16 + 8] = u1;
      }
    }
    __syncthreads();
    short8 aF0 = *(const short8*)&sA[(w * 32 + l16) * 40 + quad * 8];
    short8 aF1 = *(const short8*)&sA[(w * 32 + 16 + l16) * 40 + quad * 8];
    short8 bF0 = *(const short8*)&sB[l16 * 40 + quad * 8];
    short8 bF1 = *(const short8*)&sB[(16 + l16) * 40 + quad * 8];
    acc[0][0] = __builtin_amdgcn_mfma_f32_16x16x32_bf16(aF0, bF0, acc[0][0], 0, 0, 0);
    acc[0][1] = __builtin_amdgcn_mfma_f32_16x16x32_bf16(aF0, bF1, acc[0][1], 0, 0, 0);
    acc[1][0] = __builtin_amdgcn_mfma_f32_16x16x32_bf16(aF1, bF0, acc[1][0], 0, 0, 0);
    acc[1][1] = __builtin_amdgcn_mfma_f32_16x16x32_bf16(aF1, bF1, acc[1][1], 0, 0, 0);
    __syncthreads();
  }

#pragma unroll
  for (int ni = 0; ni < 2; ++ni) {
    const int n_g = out0 + ni * 16 + l16;
    const float vb = bb[n_g];
    const float sc = gg[n_g] * rsqrtf(vv[n_g] + EPS_BN);
    const float mu = mm[n_g];
    const float vbe = be[n_g];
#pragma unroll
    for (int mi = 0; mi < 2; ++mi) {
#pragma unroll
      for (int r = 0; r < 4; ++r) {
        const int m_g = row0 + w * 32 + mi * 16 + quad * 4 + r;
        float y = acc[mi][ni][r] + vb;
        float o = (y - mu) * sc + vbe;
        float val;
        if (MODE == 0) {
          val = lrelu(o) + resid[(size_t)m_g * 288 + n_g];
        } else {
          val = fmaxf(o, 0.f);
        }
        out[(size_t)m_g * 288 + n_g] = __float2bfloat16(val);
      }
    }
  }
}

// ---------------- K4: out = h @ cl_W2.T + cl_b2 (8192x288x2), h bf16 --------
__global__ __launch_bounds__(256) void k4_out(
    const __hip_bfloat16* __restrict__ h, const float* __restrict__ w2,
    const float* __restrict__ b2, float* __restrict__ out) {
  const int wave = threadIdx.x >> 6;
  const int lane = threadIdx.x & 63;
  const int row = blockIdx.x * 4 + wave;
  const __hip_bfloat16* hr = h + (size_t)row * 288;
  float a0 = 0.f, a1 = 0.f;
#pragma unroll
  for (int i = 0; i < 5; ++i) {
    int k = lane + 64 * i;
    if (k < 288) {
      float hv = __bfloat162float(hr[k]);
      a0 = fmaf(hv, w2[k], a0);
      a1 = fmaf(hv, w2[288 + k], a1);
    }
  }
#pragma unroll
  for (int off = 32; off; off >>= 1) {
    a0 += __shfl_xor(a0, off, 64);
    a1 += __shfl_xor(a1, off, 64);
  }
  if (lane == 0) {
    out[row * 2 + 0] = a0 + b2[0];
    out[row * 2 + 1] = a1 + b2[1];
  }
}

extern "C" void kernel_launch(void* const* d_in, const int* in_sizes, int n_in,
                              void* d_out, int out_size, void* d_ws, size_t ws_size,
                              hipStream_t stream) {
  const float* x   = (const float*)d_in[0];
  const float* cw1 = (const float*)d_in[1];  const float* cb1 = (const float*)d_in[2];
  const float* cw2 = (const float*)d_in[3];  const float* cb2 = (const float*)d_in[4];
  const float* cw3 = (const float*)d_in[5];  const float* cb3 = (const float*)d_in[6];
  const float* cw4 = (const float*)d_in[7];  const float* cb4 = (const float*)d_in[8];
  const float* cw5 = (const float*)d_in[9];  const float* cb5 = (const float*)d_in[10];
  const float* cw6 = (const float*)d_in[11]; const float* cb6 = (const float*)d_in[12];
  const float* deW = (const float*)d_in[13]; const float* deb = (const float*)d_in[14];
  const float* rsW = (const float*)d_in[15]; const float* rsb = (const float*)d_in[16];
  const float* rsg = (const float*)d_in[17]; const float* rsbe = (const float*)d_in[18];
  const float* rsm = (const float*)d_in[19]; const float* rsv = (const float*)d_in[20];
  const float* clW1 = (const float*)d_in[21]; const float* clb1 = (const float*)d_in[22];
  const float* clg = (const float*)d_in[23]; const float* clbe = (const float*)d_in[24];
  const float* clm = (const float*)d_in[25]; const float* clv = (const float*)d_in[26];
  const float* clW2 = (const float*)d_in[27]; const float* clb2 = (const float*)d_in[28];

  short* ws   = (short*)d_ws;
  short* epre = ws;                        // 16384*192 bf16 (6.3 MB)
  short* h    = ws;                        // reuse after K2 consumed epre (4.7 MB)
  short* ce   = ws + 16384 * 192;          // 16384*288 bf16 (9.4 MB)
  short* wB2  = ce + 16384 * 288;          // 288*192 bf16
  short* wB3  = wB2 + 288 * 192;           // 288*576 bf16

  hipLaunchKernelGGL(k0_cast, dim3(128), dim3(256), 0, stream,
                     rsW, clW1, (__hip_bfloat16*)wB2, (__hip_bfloat16*)wB3);
  hipLaunchKernelGGL(k1_persample, dim3(16384), dim3(256), 0, stream, x,
                     cw1, cb1, cw2, cb2, cw3, cb3, cw4, cb4, cw5, cb5, cw6, cb6,
                     deW, deb, (__hip_bfloat16*)epre);
  // K2: M=16384, K=192, A=epre -> ce (bf16), residual x
  hipLaunchKernelGGL((gemm_mfma<192, 192, 0>), dim3(128 * 9), dim3(256), 0, stream,
                     epre, wB2, rsb, rsg, rsbe, rsm, rsv, x, (__hip_bfloat16*)ce);
  // K3: M=8192, K=576, A=ce -> h (bf16)
  hipLaunchKernelGGL((gemm_mfma<576, 576, 1>), dim3(64 * 9), dim3(256), 0, stream,
                     ce, wB3, clb1, clg, clbe, clm, clv, (const float*)nullptr,
                     (__hip_bfloat16*)h);
  hipLaunchKernelGGL(k4_out, dim3(2048), dim3(256), 0, stream,
                     (const __hip_bfloat16*)h, clW2, clb2, (float*)d_out);
}